// Round 11
// baseline (116.998 us; speedup 1.0000x reference)
//
#include <hip/hip_runtime.h>
#include <math.h>

// Quantum circuit simulator: BATCH=2048 states x 1024 complex amplitudes,
// QDEPTH=8 layers of StronglyEntanglingLayers (10 Rot gates + 10 CNOTs).
//
// Round-11 = round-9 dataflow (validated 53.5us best) + PACKED FP32 math.
// Cross-round counter model: VALU busy TIME is the invariant bottleneck
// (36/38/33 us in r7/r9/r10); DS ~15us; occupancy moves don't pay (r10:
// +occupancy was cancelled by b128-write bank conflicts 3.7e6 + doubled
// scattered reads). So attack VALU inst count: state held as canonically
// packed complex v2f=(re,im) per amplitude; every complex MAC c*z =
// z*cr + J(z)*ci with J(z)=(-z.y,z.x) -> v_pk_fma_f32 (VOP3P dual FP32),
// halving the FMA core. Dataflow per layer (unchanged from r9):
//  - wires 9..6 (t-bits): register-local 2x2 updates.
//  - wires 5..2 (lane xor 1,2,4,8): DPP row ops (VALU pipe).
//  - wires 1,0 (lane xor 16,32): __shfl_xor.
//  - CNOT stage: composed GF(2)-linear permutation via one LDS round trip,
//    t-major b32 SoA word(i) = (i&15)*64 + (i>>4) -- the ONLY layout
//    measured conflict-free (r8 float2/b64: 7.3e6 conflicts; r10 lane-major
//    b128: 3.7e6; this: 1.3e5). XOR-decomposed address tables in d_ws.
// No __syncthreads (single wave per state; per-wave DS ops are in-order).

#define WIRES   10
#define NSTATE  1024
#define QDEPTH  8
#define NBATCH  2048
#define NGATES  (QDEPTH * WIRES)

typedef float v2f __attribute__((ext_vector_type(2)));

// ws layout (floats/ints, 4 B each):
//   [0   .. 640)  gate coeffs: gate gi=(l*10+q): u00r,u00i,u01r,u01i,u10r,u10i,u11r,u11i
//   [640 .. 768)  int gt[l*16+t]    = word(g_l(t))
//   [768 .. 1280) int glane[l*64+v] = word(g_l(v<<4))
#define WS_WORDS 1280

__device__ __forceinline__ int perm_g(int j, int r) {
#pragma unroll
    for (int q = WIRES - 1; q >= 0; --q) {
        const int cb = 9 - q;
        const int tb = 9 - ((q + r) % WIRES);
        j ^= ((j >> cb) & 1) << tb;
    }
    return j;
}

__global__ __launch_bounds__(1024) void qprep(
    const float* __restrict__ weights, float* __restrict__ ws)
{
    const int tid = threadIdx.x;
    if (tid < NGATES) {
        const float phi   = tanhf(weights[tid * 3 + 0]);
        const float theta = tanhf(weights[tid * 3 + 1]);
        const float omega = tanhf(weights[tid * 3 + 2]);
        const float c  = cosf(theta * 0.5f);
        const float sn = sinf(theta * 0.5f);
        const float a  = 0.5f * (phi + omega);
        const float bb = 0.5f * (phi - omega);
        const float ca = cosf(a),  sa = sinf(a);
        const float cb = cosf(bb), sb = sinf(bb);
        // U00 = e^{-ia} c ; U01 = -e^{+ib} s ; U10 = e^{-ib} s ; U11 = e^{+ia} c
        ws[tid * 8 + 0] =  ca * c;  ws[tid * 8 + 1] = -sa * c;
        ws[tid * 8 + 2] = -cb * sn; ws[tid * 8 + 3] = -sb * sn;
        ws[tid * 8 + 4] =  cb * sn; ws[tid * 8 + 5] = -sb * sn;
        ws[tid * 8 + 6] =  ca * c;  ws[tid * 8 + 7] =  sa * c;
    }
    int* wsI = (int*)ws;
    if (tid >= 128 && tid < 256) {          // gt table: 8 layers x 16 t
        const int e = tid - 128, l = e >> 4, t = e & 15;
        const int j = perm_g(t, (l % (WIRES - 1)) + 1);
        wsI[640 + e] = ((j & 15) << 6) | (j >> 4);
    }
    if (tid >= 256 && tid < 768) {          // glane table: 8 layers x 64 lanes
        const int e = tid - 256, l = e >> 6, v = e & 63;
        const int j = perm_g(v << 4, (l % (WIRES - 1)) + 1);
        wsI[768 + e] = ((j & 15) << 6) | (j >> 4);
    }
}

// DPP cross-lane move (VALU pipe, rows of 16 lanes) — validated rounds 9/10
template<int CTRL>
__device__ __forceinline__ float dppmov(float x) {
    return __int_as_float(__builtin_amdgcn_update_dpp(
        0, __float_as_int(x), CTRL, 0xF, 0xF, true));
}
#define FX1(v)  dppmov<0xB1>(v)
#define FX2(v)  dppmov<0x4E>(v)
#define FX4(v)  dppmov<0x1B>(dppmov<0x141>(v))
#define FX8(v)  dppmov<0x128>(v)
#define FX16(v) __shfl_xor((v), 16, 64)
#define FX32(v) __shfl_xor((v), 32, 64)

// local 2x2 gate along t-bit `mask`, packed complex math
#define APPLY_LOCAL(uptr, mask)                                               \
    {                                                                         \
        const float* __restrict__ u = (uptr);                                 \
        const float u00r=u[0], u00i=u[1], u01r=u[2], u01i=u[3];               \
        const float u10r=u[4], u10i=u[5], u11r=u[6], u11i=u[7];               \
        _Pragma("unroll")                                                     \
        for (int t0 = 0; t0 < 16; ++t0) {                                     \
            if (t0 & (mask)) continue;                                        \
            const int t1 = t0 | (mask);                                       \
            const v2f a0 = z[t0], a1 = z[t1];                                 \
            const v2f j0 = (v2f){-a0.y, a0.x};                                \
            const v2f j1 = (v2f){-a1.y, a1.x};                                \
            z[t0] = a0*u00r + j0*u00i + a1*u01r + j1*u01i;                    \
            z[t1] = a0*u10r + j0*u10i + a1*u11r + j1*u11i;                    \
        }                                                                     \
    }

// gate on lane-bit J (wire W), partner value via FETCH, packed complex math
#define LANE_GATE(W, J, FETCH)                                                \
    {                                                                         \
        const float* __restrict__ u = gw + (W) * 8;                           \
        const bool hi = (lane >> (J)) & 1;                                    \
        const float c0r = hi ? u[6] : u[0], c0i = hi ? u[7] : u[1];           \
        const float c1r = hi ? u[4] : u[2], c1i = hi ? u[5] : u[3];           \
        _Pragma("unroll")                                                     \
        for (int t = 0; t < 16; ++t) {                                        \
            v2f p;                                                            \
            p.x = FETCH(z[t].x);                                              \
            p.y = FETCH(z[t].y);                                              \
            const v2f s  = z[t];                                              \
            const v2f js = (v2f){-s.y, s.x};                                  \
            const v2f jp = (v2f){-p.y, p.x};                                  \
            z[t] = s*c0r + js*c0i + p*c1r + jp*c1i;                           \
        }                                                                     \
    }

__global__ __launch_bounds__(64) void qsim_wave(
    const float* __restrict__ x,
    const float* __restrict__ ws,
    float* __restrict__ out,
    const int interleaved)
{
    __shared__ float lre[NSTATE];
    __shared__ float lim[NSTATE];
    const int lane = threadIdx.x;           // 0..63
    const int b    = blockIdx.x;
    const int* __restrict__ wsI = (const int*)ws;

    v2f z[16];                              // packed complex amplitudes

    // ---- load 16 contiguous amplitudes (real input, imag = 0) ----
    const float4* __restrict__ x4 =
        (const float4*)(x + ((size_t)b << 10) + (lane << 4));
#pragma unroll
    for (int k = 0; k < 4; ++k) {
        const float4 v = x4[k];
        z[4*k+0] = (v2f){v.x, 0.f};
        z[4*k+1] = (v2f){v.y, 0.f};
        z[4*k+2] = (v2f){v.z, 0.f};
        z[4*k+3] = (v2f){v.w, 0.f};
    }

    for (int l = 0; l < QDEPTH; ++l) {
        const float* __restrict__ gw = ws + l * 80;

        // ---- local-bit gates: t-bits 0..3 = wires 9..6 (register-only) ----
        APPLY_LOCAL(gw + 9*8, 1)
        APPLY_LOCAL(gw + 8*8, 2)
        APPLY_LOCAL(gw + 7*8, 4)
        APPLY_LOCAL(gw + 6*8, 8)

        // ---- lane-bit gates: wires 5..2 on VALU (DPP), wires 1,0 via shfl ----
        LANE_GATE(5, 0, FX1)
        LANE_GATE(4, 1, FX2)
        LANE_GATE(3, 2, FX4)
        LANE_GATE(2, 3, FX8)
        LANE_GATE(1, 4, FX16)
        LANE_GATE(0, 5, FX32)

        // ---- CNOT stage: new[i] = old[g(i)] via one LDS round trip ----
        // t-major b32 SoA, word(i) = t*64 + lane (bank = lane mod 32: free)
#pragma unroll
        for (int t = 0; t < 16; ++t) {
            lre[t * 64 + lane] = z[t].x;
            lim[t * 64 + lane] = z[t].y;
        }
        // single wave: per-wave DS ops execute in order; no barrier needed
        const int ga = wsI[768 + l * 64 + lane];    // word(g(lane<<4))
#pragma unroll
        for (int t = 0; t < 16; ++t) {
            const int a = ga ^ wsI[640 + l * 16 + t];   // ^ word(g(t))
            z[t] = (v2f){lre[a], lim[a]};
        }
    }

    // ---- epilogue ----
    if (interleaved) {
        float2* __restrict__ o2 = (float2*)out;
#pragma unroll
        for (int t = 0; t < 16; ++t)
            o2[((size_t)b << 10) + (lane << 4) + t] = make_float2(z[t].x, z[t].y);
    } else {
        // harness compares real part only (complex64 expected cast to float32)
        float4* __restrict__ o4 = (float4*)(out + ((size_t)b << 10) + (lane << 4));
#pragma unroll
        for (int k = 0; k < 4; ++k)
            o4[k] = make_float4(z[4*k+0].x, z[4*k+1].x, z[4*k+2].x, z[4*k+3].x);
    }
}

// ---------------- validated round-6 fallback (ws too small) ----------------
__global__ __launch_bounds__(256) void qcircuit_kernel(
    const float* __restrict__ x, const float* __restrict__ weights,
    float* __restrict__ out, const int interleaved)
{
    __shared__ float s_re[NSTATE];
    __shared__ float s_im[NSTATE];
    __shared__ float s_g[NGATES][8];
    const int tid = threadIdx.x;
    const int b   = blockIdx.x;
    if (tid < NGATES) {
        const float phi   = tanhf(weights[tid * 3 + 0]);
        const float theta = tanhf(weights[tid * 3 + 1]);
        const float omega = tanhf(weights[tid * 3 + 2]);
        const float c  = cosf(theta * 0.5f);
        const float sn = sinf(theta * 0.5f);
        const float a  = 0.5f * (phi + omega);
        const float bb = 0.5f * (phi - omega);
        const float ca = cosf(a),  sa = sinf(a);
        const float cb = cosf(bb), sb = sinf(bb);
        s_g[tid][0] =  ca * c;  s_g[tid][1] = -sa * c;
        s_g[tid][2] = -cb * sn; s_g[tid][3] = -sb * sn;
        s_g[tid][4] =  cb * sn; s_g[tid][5] = -sb * sn;
        s_g[tid][6] =  ca * c;  s_g[tid][7] =  sa * c;
    }
#pragma unroll
    for (int k = 0; k < 4; ++k) {
        const int i = tid + 256 * k;
        s_re[i] = x[b * NSTATE + i];
        s_im[i] = 0.0f;
    }
    __syncthreads();
    for (int l = 0; l < QDEPTH; ++l) {
        for (int q = 0; q < WIRES; ++q) {
            const int gi = l * WIRES + q;
            const float u00r = s_g[gi][0], u00i = s_g[gi][1];
            const float u01r = s_g[gi][2], u01i = s_g[gi][3];
            const float u10r = s_g[gi][4], u10i = s_g[gi][5];
            const float u11r = s_g[gi][6], u11i = s_g[gi][7];
            const int sh = 9 - q;
            const int m  = 1 << sh;
#pragma unroll
            for (int k = 0; k < 2; ++k) {
                const int p  = tid + 256 * k;
                const int i0 = ((p >> sh) << (sh + 1)) | (p & (m - 1));
                const int i1 = i0 | m;
                const float a0r = s_re[i0], a0i = s_im[i0];
                const float a1r = s_re[i1], a1i = s_im[i1];
                s_re[i0] = u00r*a0r - u00i*a0i + u01r*a1r - u01i*a1i;
                s_im[i0] = u00r*a0i + u00i*a0r + u01r*a1i + u01i*a1r;
                s_re[i1] = u10r*a0r - u10i*a0i + u11r*a1r - u11i*a1i;
                s_im[i1] = u10r*a0i + u10i*a0r + u11r*a1i + u11i*a1r;
            }
            __syncthreads();
        }
        const int r = (l % (WIRES - 1)) + 1;
        float vr[4], vi[4];
#pragma unroll
        for (int k = 0; k < 4; ++k) {
            const int i = tid + 256 * k;
            const int j = perm_g(i, r);
            vr[k] = s_re[j]; vi[k] = s_im[j];
        }
        __syncthreads();
#pragma unroll
        for (int k = 0; k < 4; ++k) {
            const int i = tid + 256 * k;
            s_re[i] = vr[k]; s_im[i] = vi[k];
        }
        __syncthreads();
    }
    if (interleaved) {
#pragma unroll
        for (int k = 0; k < 4; ++k) {
            const int i  = tid + 256 * k;
            const int fi = 2 * (b * NSTATE + i);
            out[fi + 0] = s_re[i];
            out[fi + 1] = s_im[i];
        }
    } else {
#pragma unroll
        for (int k = 0; k < 4; ++k) {
            const int i = tid + 256 * k;
            out[b * NSTATE + i] = s_re[i];
        }
    }
}

extern "C" void kernel_launch(void* const* d_in, const int* in_sizes, int n_in,
                              void* d_out, int out_size, void* d_ws, size_t ws_size,
                              hipStream_t stream) {
    const float* x       = (const float*)d_in[0];   // (2048,1,32,32) f32
    const float* weights = (const float*)d_in[1];   // (8,10,3) f32
    float* out = (float*)d_out;
    const int interleaved = (out_size >= 2 * NBATCH * NSTATE) ? 1 : 0;

    if (ws_size >= WS_WORDS * sizeof(float)) {
        float* ws = (float*)d_ws;
        qprep<<<1, 1024, 0, stream>>>(weights, ws);
        qsim_wave<<<NBATCH, 64, 0, stream>>>(x, ws, out, interleaved);
    } else {
        qcircuit_kernel<<<NBATCH, 256, 0, stream>>>(x, weights, out, interleaved);
    }
}

// Round 12
// 115.519 us; speedup vs baseline: 1.0128x; 1.0128x over previous
//
#include <hip/hip_runtime.h>
#include <math.h>

// Quantum circuit simulator: BATCH=2048 states x 1024 complex amplitudes,
// QDEPTH=8 layers of StronglyEntanglingLayers (10 Rot gates + 10 CNOTs).
//
// Round-12 = round-10 (2 waves/state, 4 waves/SIMD) with its two measured
// defects fixed:
//  (a) LDS staging is t-major b32 SoA: word(i) = (i&7)*128 + (i>>3).
//      Writes hit bank tid%32 (2-way, free) -- r10's lane-major b128 writes
//      hit banks {0,8,16,24} (3.67e6 conflict cycles). word() is a bit
//      permutation => GF(2)-linear => XOR tables live in word space;
//      partner j^512 -> jw^64; wire-0 hi bit = bit6 of jw.
//  (b) double-buffered LDS (16 KB) -> ONE barrier per layer (8 total).
// Layout: i = (w<<9)|(lane<<3)|t, tid = (w<<6)|lane.
//  - t-bits 0,1,2 = wires 9,8,7: register-local.
//  - lane bits 0..3 = wires 6,5,4,3: DPP row ops (VALU pipe, r9-validated).
//  - lane bits 4,5 = wires 2,1: __shfl_xor.
//  - wave bit 9 = wire 0: folded into CNOT permutation read
//      new[i] = c0*psi[g(i)] + c1*psi[g(i)^512]   (r10-validated math).
// Cross-round model: VALU busy TIME invariant ~38us, DS ~15-20us; at 2
// waves/SIMD (r9) they serialize (53.5us); 4 waves/SIMD overlaps them.

#define WIRES   10
#define NSTATE  1024
#define QDEPTH  8
#define NBATCH  2048
#define NGATES  (QDEPTH * WIRES)

// ws layout (4-B words):
//   [0   .. 640)   gate coeffs (l*10+q): u00r,u00i,u01r,u01i,u10r,u10i,u11r,u11i
//   [640 .. 704)   int gt8[l*8 + t]    = word(g_l(t)),  t in [0,8)
//   [704 .. 1728)  int gl[l*128 + tid] = word(g_l((tid>>6)<<9 | (tid&63)<<3))
#define WS_WORDS 1728

__device__ __forceinline__ int perm_g(int j, int r) {
#pragma unroll
    for (int q = WIRES - 1; q >= 0; --q) {
        const int cb = 9 - q;
        const int tb = 9 - ((q + r) % WIRES);
        j ^= ((j >> cb) & 1) << tb;
    }
    return j;
}
__device__ __forceinline__ int wordof(int j) {   // bit permutation (linear)
    return ((j & 7) << 7) | (j >> 3);
}

__global__ __launch_bounds__(1024) void qprep(
    const float* __restrict__ weights, float* __restrict__ ws)
{
    const int tid = threadIdx.x;
    if (tid < NGATES) {
        const float phi   = tanhf(weights[tid * 3 + 0]);
        const float theta = tanhf(weights[tid * 3 + 1]);
        const float omega = tanhf(weights[tid * 3 + 2]);
        const float c  = cosf(theta * 0.5f);
        const float sn = sinf(theta * 0.5f);
        const float a  = 0.5f * (phi + omega);
        const float bb = 0.5f * (phi - omega);
        const float ca = cosf(a),  sa = sinf(a);
        const float cb = cosf(bb), sb = sinf(bb);
        // U00 = e^{-ia} c ; U01 = -e^{+ib} s ; U10 = e^{-ib} s ; U11 = e^{+ia} c
        ws[tid * 8 + 0] =  ca * c;  ws[tid * 8 + 1] = -sa * c;
        ws[tid * 8 + 2] = -cb * sn; ws[tid * 8 + 3] = -sb * sn;
        ws[tid * 8 + 4] =  cb * sn; ws[tid * 8 + 5] = -sb * sn;
        ws[tid * 8 + 6] =  ca * c;  ws[tid * 8 + 7] =  sa * c;
    }
    int* wsI = (int*)ws;
    if (tid >= 128 && tid < 192) {          // gt8: 8 layers x 8 t values
        const int e = tid - 128, l = e >> 3, t = e & 7;
        wsI[640 + e] = wordof(perm_g(t, (l % (WIRES - 1)) + 1));
    }
    {                                       // gl: 8 layers x 128 thread bases
        const int l = tid >> 7, e = tid & 127;
        const int i0 = ((e >> 6) << 9) | ((e & 63) << 3);
        wsI[704 + tid] = wordof(perm_g(i0, (l % (WIRES - 1)) + 1));
    }
}

// DPP cross-lane move (VALU pipe, rows of 16 lanes) — validated r9/r10
template<int CTRL>
__device__ __forceinline__ float dppmov(float x) {
    return __int_as_float(__builtin_amdgcn_update_dpp(
        0, __float_as_int(x), CTRL, 0xF, 0xF, true));
}
#define FX1(v)  dppmov<0xB1>(v)
#define FX2(v)  dppmov<0x4E>(v)
#define FX4(v)  dppmov<0x1B>(dppmov<0x141>(v))
#define FX8(v)  dppmov<0x128>(v)
#define FX16(v) __shfl_xor((v), 16, 64)
#define FX32(v) __shfl_xor((v), 32, 64)

#define APPLY_LOCAL8(uptr, mask)                                              \
    {                                                                         \
        const float* __restrict__ u = (uptr);                                 \
        const float u00r=u[0], u00i=u[1], u01r=u[2], u01i=u[3];               \
        const float u10r=u[4], u10i=u[5], u11r=u[6], u11i=u[7];               \
        _Pragma("unroll")                                                     \
        for (int t0 = 0; t0 < 8; ++t0) {                                      \
            if (t0 & (mask)) continue;                                        \
            const int t1 = t0 | (mask);                                       \
            const float a0r = re[t0], a0i = im[t0];                           \
            const float a1r = re[t1], a1i = im[t1];                           \
            re[t0] = u00r*a0r - u00i*a0i + u01r*a1r - u01i*a1i;               \
            im[t0] = u00r*a0i + u00i*a0r + u01r*a1i + u01i*a1r;               \
            re[t1] = u10r*a0r - u10i*a0i + u11r*a1r - u11i*a1i;               \
            im[t1] = u10r*a0i + u10i*a0r + u11r*a1i + u11i*a1r;               \
        }                                                                     \
    }

#define LANE_GATE8(W, J, FETCH)                                               \
    {                                                                         \
        const float* __restrict__ u = gw + (W) * 8;                           \
        const bool hi = (lane >> (J)) & 1;                                    \
        const float c0r = hi ? u[6] : u[0], c0i = hi ? u[7] : u[1];           \
        const float c1r = hi ? u[4] : u[2], c1i = hi ? u[5] : u[3];           \
        _Pragma("unroll")                                                     \
        for (int t = 0; t < 8; ++t) {                                         \
            const float pr = FETCH(re[t]);                                    \
            const float pi = FETCH(im[t]);                                    \
            const float sr = re[t], si = im[t];                               \
            re[t] = c0r*sr - c0i*si + c1r*pr - c1i*pi;                        \
            im[t] = c0r*si + c0i*sr + c1r*pi + c1i*pr;                        \
        }                                                                     \
    }

__global__ __launch_bounds__(128) void qsim2(
    const float* __restrict__ x,
    const float* __restrict__ ws,
    float* __restrict__ out,
    const int interleaved)
{
    __shared__ float lre[2][NSTATE];        // double-buffered: 1 barrier/layer
    __shared__ float lim[2][NSTATE];
    const int tid  = threadIdx.x;           // 0..127
    const int lane = tid & 63;
    const int b    = blockIdx.x;
    const int i0   = ((tid >> 6) << 9) | (lane << 3);   // base amp index
    const int* __restrict__ wsI = (const int*)ws;

    float re[8], im[8];

    // ---- load 8 contiguous amplitudes (real input, imag = 0) ----
    const float4* __restrict__ x4 =
        (const float4*)(x + ((size_t)b << 10) + i0);
    {
        const float4 v0 = x4[0], v1 = x4[1];
        re[0]=v0.x; re[1]=v0.y; re[2]=v0.z; re[3]=v0.w;
        re[4]=v1.x; re[5]=v1.y; re[6]=v1.z; re[7]=v1.w;
#pragma unroll
        for (int t = 0; t < 8; ++t) im[t] = 0.f;
    }

    for (int l = 0; l < QDEPTH; ++l) {
        const float* __restrict__ gw = ws + l * 80;
        float* __restrict__ bre = lre[l & 1];
        float* __restrict__ bim = lim[l & 1];

        // ---- local gates: t-bits 0,1,2 = wires 9,8,7 ----
        APPLY_LOCAL8(gw + 9*8, 1)
        APPLY_LOCAL8(gw + 8*8, 2)
        APPLY_LOCAL8(gw + 7*8, 4)

        // ---- lane-bit gates: wires 6..3 on DPP, wires 2,1 via shfl ----
        LANE_GATE8(6, 0, FX1)
        LANE_GATE8(5, 1, FX2)
        LANE_GATE8(4, 2, FX4)
        LANE_GATE8(3, 3, FX8)
        LANE_GATE8(2, 4, FX16)
        LANE_GATE8(1, 5, FX32)

        // ---- stage to LDS, t-major b32 (bank = tid%32: conflict-free) ----
#pragma unroll
        for (int t = 0; t < 8; ++t) {
            bre[t * 128 + tid] = re[t];
            bim[t * 128 + tid] = im[t];
        }
        __syncthreads();

        // ---- wire-0 gate folded into CNOT permutation read (word space) ----
        // new[i] = c0*psi[j] + c1*psi[j^512]; word(j^512)=jw^64; hi=bit6(jw)
        const float* __restrict__ u0 = gw;          // wire 0 coeffs
        const int glw = wsI[704 + l * 128 + tid];   // word(g(i0))
#pragma unroll
        for (int t = 0; t < 8; ++t) {
            const int jw  = glw ^ wsI[640 + l * 8 + t];
            const int jpw = jw ^ 64;
            const float sr = bre[jw],  si = bim[jw];
            const float pr = bre[jpw], pi = bim[jpw];
            const bool hib = (jw >> 6) & 1;
            const float c0r = hib ? u0[6] : u0[0], c0i = hib ? u0[7] : u0[1];
            const float c1r = hib ? u0[4] : u0[2], c1i = hib ? u0[5] : u0[3];
            re[t] = c0r*sr - c0i*si + c1r*pr - c1i*pi;
            im[t] = c0r*si + c0i*sr + c1r*pi + c1i*pr;
        }
        // no second barrier: next layer writes the OTHER buffer; a buffer is
        // re-written only two layers later, after an intervening barrier and
        // the sibling wave's reads (data-dependency ordered before its writes)
    }

    // ---- epilogue ----
    if (interleaved) {
        float4* __restrict__ o4 = (float4*)(out + 2 * (((size_t)b << 10) + i0));
        o4[0] = make_float4(re[0], im[0], re[1], im[1]);
        o4[1] = make_float4(re[2], im[2], re[3], im[3]);
        o4[2] = make_float4(re[4], im[4], re[5], im[5]);
        o4[3] = make_float4(re[6], im[6], re[7], im[7]);
    } else {
        // harness compares real part only (complex64 expected cast to f32)
        float4* __restrict__ o4 = (float4*)(out + ((size_t)b << 10) + i0);
        o4[0] = make_float4(re[0], re[1], re[2], re[3]);
        o4[1] = make_float4(re[4], re[5], re[6], re[7]);
    }
}

// ---------------- validated round-6 fallback (ws too small) ----------------
__global__ __launch_bounds__(256) void qcircuit_kernel(
    const float* __restrict__ x, const float* __restrict__ weights,
    float* __restrict__ out, const int interleaved)
{
    __shared__ float s_re[NSTATE];
    __shared__ float s_im[NSTATE];
    __shared__ float s_g[NGATES][8];
    const int tid = threadIdx.x;
    const int b   = blockIdx.x;
    if (tid < NGATES) {
        const float phi   = tanhf(weights[tid * 3 + 0]);
        const float theta = tanhf(weights[tid * 3 + 1]);
        const float omega = tanhf(weights[tid * 3 + 2]);
        const float c  = cosf(theta * 0.5f);
        const float sn = sinf(theta * 0.5f);
        const float a  = 0.5f * (phi + omega);
        const float bb = 0.5f * (phi - omega);
        const float ca = cosf(a),  sa = sinf(a);
        const float cb = cosf(bb), sb = sinf(bb);
        s_g[tid][0] =  ca * c;  s_g[tid][1] = -sa * c;
        s_g[tid][2] = -cb * sn; s_g[tid][3] = -sb * sn;
        s_g[tid][4] =  cb * sn; s_g[tid][5] = -sb * sn;
        s_g[tid][6] =  ca * c;  s_g[tid][7] =  sa * c;
    }
#pragma unroll
    for (int k = 0; k < 4; ++k) {
        const int i = tid + 256 * k;
        s_re[i] = x[b * NSTATE + i];
        s_im[i] = 0.0f;
    }
    __syncthreads();
    for (int l = 0; l < QDEPTH; ++l) {
        for (int q = 0; q < WIRES; ++q) {
            const int gi = l * WIRES + q;
            const float u00r = s_g[gi][0], u00i = s_g[gi][1];
            const float u01r = s_g[gi][2], u01i = s_g[gi][3];
            const float u10r = s_g[gi][4], u10i = s_g[gi][5];
            const float u11r = s_g[gi][6], u11i = s_g[gi][7];
            const int sh = 9 - q;
            const int m  = 1 << sh;
#pragma unroll
            for (int k = 0; k < 2; ++k) {
                const int p  = tid + 256 * k;
                const int i0 = ((p >> sh) << (sh + 1)) | (p & (m - 1));
                const int i1 = i0 | m;
                const float a0r = s_re[i0], a0i = s_im[i0];
                const float a1r = s_re[i1], a1i = s_im[i1];
                s_re[i0] = u00r*a0r - u00i*a0i + u01r*a1r - u01i*a1i;
                s_im[i0] = u00r*a0i + u00i*a0r + u01r*a1i + u01i*a1r;
                s_re[i1] = u10r*a0r - u10i*a0i + u11r*a1r - u11i*a1i;
                s_im[i1] = u10r*a0i + u10i*a0r + u11r*a1i + u11i*a1r;
            }
            __syncthreads();
        }
        const int r = (l % (WIRES - 1)) + 1;
        float vr[4], vi[4];
#pragma unroll
        for (int k = 0; k < 4; ++k) {
            const int i = tid + 256 * k;
            const int j = perm_g(i, r);
            vr[k] = s_re[j]; vi[k] = s_im[j];
        }
        __syncthreads();
#pragma unroll
        for (int k = 0; k < 4; ++k) {
            const int i = tid + 256 * k;
            s_re[i] = vr[k]; s_im[i] = vi[k];
        }
        __syncthreads();
    }
    if (interleaved) {
#pragma unroll
        for (int k = 0; k < 4; ++k) {
            const int i  = tid + 256 * k;
            const int fi = 2 * (b * NSTATE + i);
            out[fi + 0] = s_re[i];
            out[fi + 1] = s_im[i];
        }
    } else {
#pragma unroll
        for (int k = 0; k < 4; ++k) {
            const int i = tid + 256 * k;
            out[b * NSTATE + i] = s_re[i];
        }
    }
}

extern "C" void kernel_launch(void* const* d_in, const int* in_sizes, int n_in,
                              void* d_out, int out_size, void* d_ws, size_t ws_size,
                              hipStream_t stream) {
    const float* x       = (const float*)d_in[0];   // (2048,1,32,32) f32
    const float* weights = (const float*)d_in[1];   // (8,10,3) f32
    float* out = (float*)d_out;
    const int interleaved = (out_size >= 2 * NBATCH * NSTATE) ? 1 : 0;

    if (ws_size >= WS_WORDS * sizeof(float)) {
        float* ws = (float*)d_ws;
        qprep<<<1, 1024, 0, stream>>>(weights, ws);
        qsim2<<<NBATCH, 128, 0, stream>>>(x, ws, out, interleaved);
    } else {
        qcircuit_kernel<<<NBATCH, 256, 0, stream>>>(x, weights, out, interleaved);
    }
}

// Round 13
// 103.657 us; speedup vs baseline: 1.1287x; 1.1144x over previous
//
#include <hip/hip_runtime.h>
#include <math.h>

// Quantum circuit simulator: BATCH=2048 states x 1024 complex amplitudes,
// QDEPTH=8 layers of StronglyEntanglingLayers (10 Rot gates + 10 CNOTs).
//
// Round-13 = round-9 skeleton (validated best, 53.5us) + CORRECT fp32
// packing. Cross-round model: VALU busy TIME is the bottleneck (38us in the
// r9 structure); DS ~15us; occupancy splits inflate VALU (r10: 33us->r12:
// 46us of VALU time) and lose. r11's (re,im) packing lost to J-swizzles.
// Fix: pack over the t-dimension, re/im planes SEPARATE:
//     zr[k] = (re[t=k], re[t=k+8]),  zi[k] = (im[k], im[k+8]),  k=0..7
// Every gate update becomes element-wise v2f math with scalar wave-uniform
// coefficients -> v_pk_fma_f32 (2 FMA/inst), no swizzles. Only the mask-8
// local gate (wire 6) pairs lo<->hi of one pack: one half-swap shuffle +
// packed constants (u00r,u11r)/(u01r,u10r) -- still 2x.
// Dataflow per layer (identical to r9):
//  - wires 9..6 (t-bits 0..3): register-local (masks 1,2,4 cross-pack;
//    mask 8 intra-pack via half-swap).
//  - wires 5..2 (lane xor 1,2,4,8): DPP row ops, per-half b32 (VALU pipe).
//  - wires 1,0 (lane xor 16,32): __shfl_xor per half.
//  - CNOT stage: composed GF(2)-linear permutation, one LDS round trip,
//    t-major b32 SoA word(i) = (i&15)*64 + (i>>4) (the only layout measured
//    conflict-free: 1.3e5 vs 7.3e6 (r8 b64) / 3.7e6 (r10 b128)).
// No __syncthreads (single wave per state; per-wave DS ops in-order).

#define WIRES   10
#define NSTATE  1024
#define QDEPTH  8
#define NBATCH  2048
#define NGATES  (QDEPTH * WIRES)

typedef float v2f __attribute__((ext_vector_type(2)));
static __device__ __forceinline__ v2f s2(float x) { return (v2f){x, x}; }

// ws layout (floats/ints, 4 B each):
//   [0   .. 640)  gate coeffs gi=(l*10+q): u00r,u00i,u01r,u01i,u10r,u10i,u11r,u11i
//   [640 .. 768)  int gt[l*16+t]    = word(g_l(t))
//   [768 .. 1280) int glane[l*64+v] = word(g_l(v<<4))
#define WS_WORDS 1280

__device__ __forceinline__ int perm_g(int j, int r) {
#pragma unroll
    for (int q = WIRES - 1; q >= 0; --q) {
        const int cb = 9 - q;
        const int tb = 9 - ((q + r) % WIRES);
        j ^= ((j >> cb) & 1) << tb;
    }
    return j;
}

__global__ __launch_bounds__(1024) void qprep(
    const float* __restrict__ weights, float* __restrict__ ws)
{
    const int tid = threadIdx.x;
    if (tid < NGATES) {
        const float phi   = tanhf(weights[tid * 3 + 0]);
        const float theta = tanhf(weights[tid * 3 + 1]);
        const float omega = tanhf(weights[tid * 3 + 2]);
        const float c  = cosf(theta * 0.5f);
        const float sn = sinf(theta * 0.5f);
        const float a  = 0.5f * (phi + omega);
        const float bb = 0.5f * (phi - omega);
        const float ca = cosf(a),  sa = sinf(a);
        const float cb = cosf(bb), sb = sinf(bb);
        // U00 = e^{-ia} c ; U01 = -e^{+ib} s ; U10 = e^{-ib} s ; U11 = e^{+ia} c
        ws[tid * 8 + 0] =  ca * c;  ws[tid * 8 + 1] = -sa * c;
        ws[tid * 8 + 2] = -cb * sn; ws[tid * 8 + 3] = -sb * sn;
        ws[tid * 8 + 4] =  cb * sn; ws[tid * 8 + 5] = -sb * sn;
        ws[tid * 8 + 6] =  ca * c;  ws[tid * 8 + 7] =  sa * c;
    }
    int* wsI = (int*)ws;
    if (tid >= 128 && tid < 256) {          // gt table: 8 layers x 16 t
        const int e = tid - 128, l = e >> 4, t = e & 15;
        const int j = perm_g(t, (l % (WIRES - 1)) + 1);
        wsI[640 + e] = ((j & 15) << 6) | (j >> 4);
    }
    if (tid >= 256 && tid < 768) {          // glane table: 8 layers x 64 lanes
        const int e = tid - 256, l = e >> 6, v = e & 63;
        const int j = perm_g(v << 4, (l % (WIRES - 1)) + 1);
        wsI[768 + e] = ((j & 15) << 6) | (j >> 4);
    }
}

// DPP cross-lane move (VALU pipe, rows of 16 lanes) — validated r9/r10
template<int CTRL>
__device__ __forceinline__ float dppmov(float x) {
    return __int_as_float(__builtin_amdgcn_update_dpp(
        0, __float_as_int(x), CTRL, 0xF, 0xF, true));
}
#define FX1(v)  dppmov<0xB1>(v)
#define FX2(v)  dppmov<0x4E>(v)
#define FX4(v)  dppmov<0x1B>(dppmov<0x141>(v))
#define FX8(v)  dppmov<0x128>(v)
#define FX16(v) __shfl_xor((v), 16, 64)
#define FX32(v) __shfl_xor((v), 32, 64)

// local 2x2 gate along t-bit mask (1,2,4): partner in a DIFFERENT pack,
// matching halves -> pure packed element-wise math, scalar coeffs
#define APPLY_LOCAL_PK(uptr, mask)                                            \
    {                                                                         \
        const float* __restrict__ u = (uptr);                                 \
        const float u00r=u[0], u00i=u[1], u01r=u[2], u01i=u[3];               \
        const float u10r=u[4], u10i=u[5], u11r=u[6], u11i=u[7];               \
        _Pragma("unroll")                                                     \
        for (int k0 = 0; k0 < 8; ++k0) {                                      \
            if (k0 & (mask)) continue;                                        \
            const int k1 = k0 | (mask);                                       \
            const v2f a0r = zr[k0], a0i = zi[k0];                             \
            const v2f a1r = zr[k1], a1i = zi[k1];                             \
            zr[k0] = s2(u00r)*a0r - s2(u00i)*a0i + s2(u01r)*a1r - s2(u01i)*a1i;\
            zi[k0] = s2(u00r)*a0i + s2(u00i)*a0r + s2(u01r)*a1i + s2(u01i)*a1r;\
            zr[k1] = s2(u10r)*a0r - s2(u10i)*a0i + s2(u11r)*a1r - s2(u11i)*a1i;\
            zi[k1] = s2(u10r)*a0i + s2(u10i)*a0r + s2(u11r)*a1i + s2(u11i)*a1r;\
        }                                                                     \
    }

// gate on lane-bit J (wire W): partner via per-half FETCH, scalar coeffs
#define LANE_GATE_PK(W, J, FETCH)                                             \
    {                                                                         \
        const float* __restrict__ u = gw + (W) * 8;                           \
        const bool hi = (lane >> (J)) & 1;                                    \
        const float c0r = hi ? u[6] : u[0], c0i = hi ? u[7] : u[1];           \
        const float c1r = hi ? u[4] : u[2], c1i = hi ? u[5] : u[3];           \
        _Pragma("unroll")                                                     \
        for (int k = 0; k < 8; ++k) {                                         \
            v2f pr, pi;                                                       \
            pr.x = FETCH(zr[k].x); pr.y = FETCH(zr[k].y);                     \
            pi.x = FETCH(zi[k].x); pi.y = FETCH(zi[k].y);                     \
            const v2f sr = zr[k], si = zi[k];                                 \
            zr[k] = s2(c0r)*sr - s2(c0i)*si + s2(c1r)*pr - s2(c1i)*pi;        \
            zi[k] = s2(c0r)*si + s2(c0i)*sr + s2(c1r)*pi + s2(c1i)*pr;        \
        }                                                                     \
    }

__global__ __launch_bounds__(64) void qsim_wave(
    const float* __restrict__ x,
    const float* __restrict__ ws,
    float* __restrict__ out,
    const int interleaved)
{
    __shared__ float lre[NSTATE];
    __shared__ float lim[NSTATE];
    const int lane = threadIdx.x;           // 0..63
    const int b    = blockIdx.x;
    const int* __restrict__ wsI = (const int*)ws;

    // packed planes: zr[k] = (re[t=k], re[t=k+8]); zi likewise
    v2f zr[8], zi[8];

    // ---- load 16 contiguous amplitudes (real input, imag = 0) ----
    const float4* __restrict__ x4 =
        (const float4*)(x + ((size_t)b << 10) + (lane << 4));
    {
        const float4 v0 = x4[0], v1 = x4[1], v2 = x4[2], v3 = x4[3];
        zr[0].x=v0.x; zr[1].x=v0.y; zr[2].x=v0.z; zr[3].x=v0.w;
        zr[4].x=v1.x; zr[5].x=v1.y; zr[6].x=v1.z; zr[7].x=v1.w;
        zr[0].y=v2.x; zr[1].y=v2.y; zr[2].y=v2.z; zr[3].y=v2.w;
        zr[4].y=v3.x; zr[5].y=v3.y; zr[6].y=v3.z; zr[7].y=v3.w;
#pragma unroll
        for (int k = 0; k < 8; ++k) zi[k] = (v2f){0.f, 0.f};
    }

    for (int l = 0; l < QDEPTH; ++l) {
        const float* __restrict__ gw = ws + l * 80;

        // ---- local gates: t-bits 0,1,2 = wires 9,8,7 (cross-pack) ----
        APPLY_LOCAL_PK(gw + 9*8, 1)
        APPLY_LOCAL_PK(gw + 8*8, 2)
        APPLY_LOCAL_PK(gw + 7*8, 4)

        // ---- t-bit 3 = wire 6: lo<->hi within each pack (half-swap) ----
        {
            const float* __restrict__ u = gw + 6*8;
            const v2f pAr = (v2f){u[0], u[6]};   // (u00r, u11r)
            const v2f pAi = (v2f){u[1], u[7]};   // (u00i, u11i)
            const v2f pBr = (v2f){u[2], u[4]};   // (u01r, u10r)
            const v2f pBi = (v2f){u[3], u[5]};   // (u01i, u10i)
#pragma unroll
            for (int k = 0; k < 8; ++k) {
                const v2f r  = zr[k], i = zi[k];
                const v2f rs = __builtin_shufflevector(r, r, 1, 0);
                const v2f is = __builtin_shufflevector(i, i, 1, 0);
                zr[k] = pAr*r - pAi*i + pBr*rs - pBi*is;
                zi[k] = pAr*i + pAi*r + pBr*is + pBi*rs;
            }
        }

        // ---- lane-bit gates: wires 5..2 on DPP, wires 1,0 via shfl ----
        LANE_GATE_PK(5, 0, FX1)
        LANE_GATE_PK(4, 1, FX2)
        LANE_GATE_PK(3, 2, FX4)
        LANE_GATE_PK(2, 3, FX8)
        LANE_GATE_PK(1, 4, FX16)
        LANE_GATE_PK(0, 5, FX32)

        // ---- CNOT stage: new[i] = old[g(i)] via one LDS round trip ----
        // t-major b32 SoA, word(i) = t*64 + lane (bank = lane mod 32: free)
#pragma unroll
        for (int k = 0; k < 8; ++k) {
            lre[k * 64 + lane]         = zr[k].x;
            lre[(k + 8) * 64 + lane]   = zr[k].y;
            lim[k * 64 + lane]         = zi[k].x;
            lim[(k + 8) * 64 + lane]   = zi[k].y;
        }
        // single wave: per-wave DS ops execute in order; no barrier needed
        const int ga = wsI[768 + l * 64 + lane];    // word(g(lane<<4))
#pragma unroll
        for (int k = 0; k < 8; ++k) {
            const int a0 = ga ^ wsI[640 + l * 16 + k];
            const int a1 = ga ^ wsI[640 + l * 16 + k + 8];
            zr[k].x = lre[a0]; zi[k].x = lim[a0];
            zr[k].y = lre[a1]; zi[k].y = lim[a1];
        }
    }

    // ---- epilogue ----
    if (interleaved) {
        float2* __restrict__ o2 = (float2*)out;
        const size_t base = ((size_t)b << 10) + (lane << 4);
#pragma unroll
        for (int k = 0; k < 8; ++k) {
            o2[base + k]     = make_float2(zr[k].x, zi[k].x);
            o2[base + k + 8] = make_float2(zr[k].y, zi[k].y);
        }
    } else {
        // harness compares real part only (complex64 expected cast to float32)
        float4* __restrict__ o4 = (float4*)(out + ((size_t)b << 10) + (lane << 4));
        o4[0] = make_float4(zr[0].x, zr[1].x, zr[2].x, zr[3].x);
        o4[1] = make_float4(zr[4].x, zr[5].x, zr[6].x, zr[7].x);
        o4[2] = make_float4(zr[0].y, zr[1].y, zr[2].y, zr[3].y);
        o4[3] = make_float4(zr[4].y, zr[5].y, zr[6].y, zr[7].y);
    }
}

// ---------------- validated round-6 fallback (ws too small) ----------------
__global__ __launch_bounds__(256) void qcircuit_kernel(
    const float* __restrict__ x, const float* __restrict__ weights,
    float* __restrict__ out, const int interleaved)
{
    __shared__ float s_re[NSTATE];
    __shared__ float s_im[NSTATE];
    __shared__ float s_g[NGATES][8];
    const int tid = threadIdx.x;
    const int b   = blockIdx.x;
    if (tid < NGATES) {
        const float phi   = tanhf(weights[tid * 3 + 0]);
        const float theta = tanhf(weights[tid * 3 + 1]);
        const float omega = tanhf(weights[tid * 3 + 2]);
        const float c  = cosf(theta * 0.5f);
        const float sn = sinf(theta * 0.5f);
        const float a  = 0.5f * (phi + omega);
        const float bb = 0.5f * (phi - omega);
        const float ca = cosf(a),  sa = sinf(a);
        const float cb = cosf(bb), sb = sinf(bb);
        s_g[tid][0] =  ca * c;  s_g[tid][1] = -sa * c;
        s_g[tid][2] = -cb * sn; s_g[tid][3] = -sb * sn;
        s_g[tid][4] =  cb * sn; s_g[tid][5] = -sb * sn;
        s_g[tid][6] =  ca * c;  s_g[tid][7] =  sa * c;
    }
#pragma unroll
    for (int k = 0; k < 4; ++k) {
        const int i = tid + 256 * k;
        s_re[i] = x[b * NSTATE + i];
        s_im[i] = 0.0f;
    }
    __syncthreads();
    for (int l = 0; l < QDEPTH; ++l) {
        for (int q = 0; q < WIRES; ++q) {
            const int gi = l * WIRES + q;
            const float u00r = s_g[gi][0], u00i = s_g[gi][1];
            const float u01r = s_g[gi][2], u01i = s_g[gi][3];
            const float u10r = s_g[gi][4], u10i = s_g[gi][5];
            const float u11r = s_g[gi][6], u11i = s_g[gi][7];
            const int sh = 9 - q;
            const int m  = 1 << sh;
#pragma unroll
            for (int k = 0; k < 2; ++k) {
                const int p  = tid + 256 * k;
                const int i0 = ((p >> sh) << (sh + 1)) | (p & (m - 1));
                const int i1 = i0 | m;
                const float a0r = s_re[i0], a0i = s_im[i0];
                const float a1r = s_re[i1], a1i = s_im[i1];
                s_re[i0] = u00r*a0r - u00i*a0i + u01r*a1r - u01i*a1i;
                s_im[i0] = u00r*a0i + u00i*a0r + u01r*a1i + u01i*a1r;
                s_re[i1] = u10r*a0r - u10i*a0i + u11r*a1r - u11i*a1i;
                s_im[i1] = u10r*a0i + u10i*a0r + u11r*a1i + u11i*a1r;
            }
            __syncthreads();
        }
        const int r = (l % (WIRES - 1)) + 1;
        float vr[4], vi[4];
#pragma unroll
        for (int k = 0; k < 4; ++k) {
            const int i = tid + 256 * k;
            const int j = perm_g(i, r);
            vr[k] = s_re[j]; vi[k] = s_im[j];
        }
        __syncthreads();
#pragma unroll
        for (int k = 0; k < 4; ++k) {
            const int i = tid + 256 * k;
            s_re[i] = vr[k]; s_im[i] = vi[k];
        }
        __syncthreads();
    }
    if (interleaved) {
#pragma unroll
        for (int k = 0; k < 4; ++k) {
            const int i  = tid + 256 * k;
            const int fi = 2 * (b * NSTATE + i);
            out[fi + 0] = s_re[i];
            out[fi + 1] = s_im[i];
        }
    } else {
#pragma unroll
        for (int k = 0; k < 4; ++k) {
            const int i = tid + 256 * k;
            out[b * NSTATE + i] = s_re[i];
        }
    }
}

extern "C" void kernel_launch(void* const* d_in, const int* in_sizes, int n_in,
                              void* d_out, int out_size, void* d_ws, size_t ws_size,
                              hipStream_t stream) {
    const float* x       = (const float*)d_in[0];   // (2048,1,32,32) f32
    const float* weights = (const float*)d_in[1];   // (8,10,3) f32
    float* out = (float*)d_out;
    const int interleaved = (out_size >= 2 * NBATCH * NSTATE) ? 1 : 0;

    if (ws_size >= WS_WORDS * sizeof(float)) {
        float* ws = (float*)d_ws;
        qprep<<<1, 1024, 0, stream>>>(weights, ws);
        qsim_wave<<<NBATCH, 64, 0, stream>>>(x, ws, out, interleaved);
    } else {
        qcircuit_kernel<<<NBATCH, 256, 0, stream>>>(x, weights, out, interleaved);
    }
}

// Round 14
// 102.941 us; speedup vs baseline: 1.1366x; 1.0070x over previous
//
#include <hip/hip_runtime.h>
#include <math.h>

// Quantum circuit simulator: BATCH=2048 states x 1024 complex amplitudes,
// QDEPTH=8 layers of StronglyEntanglingLayers (10 Rot gates + 10 CNOTs).
//
// Round-14 = round-13 (validated best, 48.6us kernel) + CNOT-stage DS
// pairing. Counter model after r13: VALU busy 22.6us (t-packed v_pk_fma),
// DS ~20us (64 bpermute + 64 CNOT b32 per layer), 2 waves/SIMD -> poor
// overlap. This round: merge re/im LDS planes into ONE array so the CNOT
// stage's 4 accesses per k share a base address with dword deltas
// {0,512,1024,1536} -> SILoadStoreOptimizer merges them into
// ds_write2st64_b32 / ds_read2st64_b32 (256B-granular paired ops),
// halving CNOT DS instruction count (64 -> 32 insts/layer). Paired
// addresses are same-bank (+512/+1024 = 0 mod 32) = free 2-way regime.
// Everything else byte-identical to r13:
//  - state packed over t: zr[k]=(re[t=k],re[t=k+8]), zi likewise ->
//    element-wise v_pk_fma_f32 with scalar coeffs (halved VALU, r13 WIN).
//  - wires 9..7: cross-pack register gates; wire 6: in-pack half-swap.
//  - wires 5..2: DPP row ops (VALU pipe); wires 1,0: __shfl_xor.
//  - CNOT: composed GF(2)-linear permutation, one LDS round trip, t-major
//    b32 SoA word(i)=(i&15)*64+(i>>4) (only layout measured conflict-free:
//    1.3e5 vs 7.3e6 r8-b64 / 3.7e6 r10-b128). XOR tables in d_ws.
// No __syncthreads (single wave per state; per-wave DS ops in-order).

#define WIRES   10
#define NSTATE  1024
#define QDEPTH  8
#define NBATCH  2048
#define NGATES  (QDEPTH * WIRES)

typedef float v2f __attribute__((ext_vector_type(2)));
static __device__ __forceinline__ v2f s2(float x) { return (v2f){x, x}; }

// ws layout (floats/ints, 4 B each):
//   [0   .. 640)  gate coeffs gi=(l*10+q): u00r,u00i,u01r,u01i,u10r,u10i,u11r,u11i
//   [640 .. 768)  int gt[l*16+t]    = word(g_l(t))
//   [768 .. 1280) int glane[l*64+v] = word(g_l(v<<4))
#define WS_WORDS 1280

__device__ __forceinline__ int perm_g(int j, int r) {
#pragma unroll
    for (int q = WIRES - 1; q >= 0; --q) {
        const int cb = 9 - q;
        const int tb = 9 - ((q + r) % WIRES);
        j ^= ((j >> cb) & 1) << tb;
    }
    return j;
}

__global__ __launch_bounds__(1024) void qprep(
    const float* __restrict__ weights, float* __restrict__ ws)
{
    const int tid = threadIdx.x;
    if (tid < NGATES) {
        const float phi   = tanhf(weights[tid * 3 + 0]);
        const float theta = tanhf(weights[tid * 3 + 1]);
        const float omega = tanhf(weights[tid * 3 + 2]);
        const float c  = cosf(theta * 0.5f);
        const float sn = sinf(theta * 0.5f);
        const float a  = 0.5f * (phi + omega);
        const float bb = 0.5f * (phi - omega);
        const float ca = cosf(a),  sa = sinf(a);
        const float cb = cosf(bb), sb = sinf(bb);
        // U00 = e^{-ia} c ; U01 = -e^{+ib} s ; U10 = e^{-ib} s ; U11 = e^{+ia} c
        ws[tid * 8 + 0] =  ca * c;  ws[tid * 8 + 1] = -sa * c;
        ws[tid * 8 + 2] = -cb * sn; ws[tid * 8 + 3] = -sb * sn;
        ws[tid * 8 + 4] =  cb * sn; ws[tid * 8 + 5] = -sb * sn;
        ws[tid * 8 + 6] =  ca * c;  ws[tid * 8 + 7] =  sa * c;
    }
    int* wsI = (int*)ws;
    if (tid >= 128 && tid < 256) {          // gt table: 8 layers x 16 t
        const int e = tid - 128, l = e >> 4, t = e & 15;
        const int j = perm_g(t, (l % (WIRES - 1)) + 1);
        wsI[640 + e] = ((j & 15) << 6) | (j >> 4);
    }
    if (tid >= 256 && tid < 768) {          // glane table: 8 layers x 64 lanes
        const int e = tid - 256, l = e >> 6, v = e & 63;
        const int j = perm_g(v << 4, (l % (WIRES - 1)) + 1);
        wsI[768 + e] = ((j & 15) << 6) | (j >> 4);
    }
}

// DPP cross-lane move (VALU pipe, rows of 16 lanes) — validated r9/r10/r13
template<int CTRL>
__device__ __forceinline__ float dppmov(float x) {
    return __int_as_float(__builtin_amdgcn_update_dpp(
        0, __float_as_int(x), CTRL, 0xF, 0xF, true));
}
#define FX1(v)  dppmov<0xB1>(v)
#define FX2(v)  dppmov<0x4E>(v)
#define FX4(v)  dppmov<0x1B>(dppmov<0x141>(v))
#define FX8(v)  dppmov<0x128>(v)
#define FX16(v) __shfl_xor((v), 16, 64)
#define FX32(v) __shfl_xor((v), 32, 64)

// local 2x2 gate along t-bit mask (1,2,4): partner in a DIFFERENT pack,
// matching halves -> pure packed element-wise math, scalar coeffs
#define APPLY_LOCAL_PK(uptr, mask)                                            \
    {                                                                         \
        const float* __restrict__ u = (uptr);                                 \
        const float u00r=u[0], u00i=u[1], u01r=u[2], u01i=u[3];               \
        const float u10r=u[4], u10i=u[5], u11r=u[6], u11i=u[7];               \
        _Pragma("unroll")                                                     \
        for (int k0 = 0; k0 < 8; ++k0) {                                      \
            if (k0 & (mask)) continue;                                        \
            const int k1 = k0 | (mask);                                       \
            const v2f a0r = zr[k0], a0i = zi[k0];                             \
            const v2f a1r = zr[k1], a1i = zi[k1];                             \
            zr[k0] = s2(u00r)*a0r - s2(u00i)*a0i + s2(u01r)*a1r - s2(u01i)*a1i;\
            zi[k0] = s2(u00r)*a0i + s2(u00i)*a0r + s2(u01r)*a1i + s2(u01i)*a1r;\
            zr[k1] = s2(u10r)*a0r - s2(u10i)*a0i + s2(u11r)*a1r - s2(u11i)*a1i;\
            zi[k1] = s2(u10r)*a0i + s2(u10i)*a0r + s2(u11r)*a1i + s2(u11i)*a1r;\
        }                                                                     \
    }

// gate on lane-bit J (wire W): partner via per-half FETCH, scalar coeffs
#define LANE_GATE_PK(W, J, FETCH)                                             \
    {                                                                         \
        const float* __restrict__ u = gw + (W) * 8;                           \
        const bool hi = (lane >> (J)) & 1;                                    \
        const float c0r = hi ? u[6] : u[0], c0i = hi ? u[7] : u[1];           \
        const float c1r = hi ? u[4] : u[2], c1i = hi ? u[5] : u[3];           \
        _Pragma("unroll")                                                     \
        for (int k = 0; k < 8; ++k) {                                         \
            v2f pr, pi;                                                       \
            pr.x = FETCH(zr[k].x); pr.y = FETCH(zr[k].y);                     \
            pi.x = FETCH(zi[k].x); pi.y = FETCH(zi[k].y);                     \
            const v2f sr = zr[k], si = zi[k];                                 \
            zr[k] = s2(c0r)*sr - s2(c0i)*si + s2(c1r)*pr - s2(c1i)*pi;        \
            zi[k] = s2(c0r)*si + s2(c0i)*sr + s2(c1r)*pi + s2(c1i)*pr;        \
        }                                                                     \
    }

__global__ __launch_bounds__(64) void qsim_wave(
    const float* __restrict__ x,
    const float* __restrict__ ws,
    float* __restrict__ out,
    const int interleaved)
{
    // single LDS array: re plane at [0,1024), im plane at [1024,2048).
    // per-k CNOT accesses share a base address with dword deltas
    // {0, 512, 1024, 1536} -> pairable into ds_*2st64_b32 (offsets 0/8, 16/24)
    __shared__ float lds[2 * NSTATE];
    const int lane = threadIdx.x;           // 0..63
    const int b    = blockIdx.x;
    const int* __restrict__ wsI = (const int*)ws;

    // packed planes: zr[k] = (re[t=k], re[t=k+8]); zi likewise
    v2f zr[8], zi[8];

    // ---- load 16 contiguous amplitudes (real input, imag = 0) ----
    const float4* __restrict__ x4 =
        (const float4*)(x + ((size_t)b << 10) + (lane << 4));
    {
        const float4 v0 = x4[0], v1 = x4[1], v2 = x4[2], v3 = x4[3];
        zr[0].x=v0.x; zr[1].x=v0.y; zr[2].x=v0.z; zr[3].x=v0.w;
        zr[4].x=v1.x; zr[5].x=v1.y; zr[6].x=v1.z; zr[7].x=v1.w;
        zr[0].y=v2.x; zr[1].y=v2.y; zr[2].y=v2.z; zr[3].y=v2.w;
        zr[4].y=v3.x; zr[5].y=v3.y; zr[6].y=v3.z; zr[7].y=v3.w;
#pragma unroll
        for (int k = 0; k < 8; ++k) zi[k] = (v2f){0.f, 0.f};
    }

    for (int l = 0; l < QDEPTH; ++l) {
        const float* __restrict__ gw = ws + l * 80;

        // ---- local gates: t-bits 0,1,2 = wires 9,8,7 (cross-pack) ----
        APPLY_LOCAL_PK(gw + 9*8, 1)
        APPLY_LOCAL_PK(gw + 8*8, 2)
        APPLY_LOCAL_PK(gw + 7*8, 4)

        // ---- t-bit 3 = wire 6: lo<->hi within each pack (half-swap) ----
        {
            const float* __restrict__ u = gw + 6*8;
            const v2f pAr = (v2f){u[0], u[6]};   // (u00r, u11r)
            const v2f pAi = (v2f){u[1], u[7]};   // (u00i, u11i)
            const v2f pBr = (v2f){u[2], u[4]};   // (u01r, u10r)
            const v2f pBi = (v2f){u[3], u[5]};   // (u01i, u10i)
#pragma unroll
            for (int k = 0; k < 8; ++k) {
                const v2f r  = zr[k], i = zi[k];
                const v2f rs = __builtin_shufflevector(r, r, 1, 0);
                const v2f is = __builtin_shufflevector(i, i, 1, 0);
                zr[k] = pAr*r - pAi*i + pBr*rs - pBi*is;
                zi[k] = pAr*i + pAi*r + pBr*is + pBi*rs;
            }
        }

        // ---- lane-bit gates: wires 5..2 on DPP, wires 1,0 via shfl ----
        LANE_GATE_PK(5, 0, FX1)
        LANE_GATE_PK(4, 1, FX2)
        LANE_GATE_PK(3, 2, FX4)
        LANE_GATE_PK(2, 3, FX8)
        LANE_GATE_PK(1, 4, FX16)
        LANE_GATE_PK(0, 5, FX32)

        // ---- CNOT stage: new[i] = old[g(i)] via one LDS round trip ----
        // word(i) = t*64 + lane (bank = lane mod 32: conflict-free).
        // re[t=k] -> w, re[t=k+8] -> w+512, im planes at +1024:
        // four stores per k off one base -> 2x ds_write2st64_b32
#pragma unroll
        for (int k = 0; k < 8; ++k) {
            const int w = k * 64 + lane;
            lds[w]        = zr[k].x;
            lds[w + 512]  = zr[k].y;
            lds[w + 1024] = zi[k].x;
            lds[w + 1536] = zi[k].y;
        }
        // single wave: per-wave DS ops execute in order; no barrier needed
        const int ga = wsI[768 + l * 64 + lane];    // word(g(lane<<4))
#pragma unroll
        for (int k = 0; k < 8; ++k) {
            const int a0 = ga ^ wsI[640 + l * 16 + k];
            const int a1 = ga ^ wsI[640 + l * 16 + k + 8];
            // (re,im) per source share base -> 2x ds_read2st64_b32
            zr[k].x = lds[a0]; zi[k].x = lds[a0 + 1024];
            zr[k].y = lds[a1]; zi[k].y = lds[a1 + 1024];
        }
    }

    // ---- epilogue ----
    if (interleaved) {
        float2* __restrict__ o2 = (float2*)out;
        const size_t base = ((size_t)b << 10) + (lane << 4);
#pragma unroll
        for (int k = 0; k < 8; ++k) {
            o2[base + k]     = make_float2(zr[k].x, zi[k].x);
            o2[base + k + 8] = make_float2(zr[k].y, zi[k].y);
        }
    } else {
        // harness compares real part only (complex64 expected cast to float32)
        float4* __restrict__ o4 = (float4*)(out + ((size_t)b << 10) + (lane << 4));
        o4[0] = make_float4(zr[0].x, zr[1].x, zr[2].x, zr[3].x);
        o4[1] = make_float4(zr[4].x, zr[5].x, zr[6].x, zr[7].x);
        o4[2] = make_float4(zr[0].y, zr[1].y, zr[2].y, zr[3].y);
        o4[3] = make_float4(zr[4].y, zr[5].y, zr[6].y, zr[7].y);
    }
}

// ---------------- validated round-6 fallback (ws too small) ----------------
__global__ __launch_bounds__(256) void qcircuit_kernel(
    const float* __restrict__ x, const float* __restrict__ weights,
    float* __restrict__ out, const int interleaved)
{
    __shared__ float s_re[NSTATE];
    __shared__ float s_im[NSTATE];
    __shared__ float s_g[NGATES][8];
    const int tid = threadIdx.x;
    const int b   = blockIdx.x;
    if (tid < NGATES) {
        const float phi   = tanhf(weights[tid * 3 + 0]);
        const float theta = tanhf(weights[tid * 3 + 1]);
        const float omega = tanhf(weights[tid * 3 + 2]);
        const float c  = cosf(theta * 0.5f);
        const float sn = sinf(theta * 0.5f);
        const float a  = 0.5f * (phi + omega);
        const float bb = 0.5f * (phi - omega);
        const float ca = cosf(a),  sa = sinf(a);
        const float cb = cosf(bb), sb = sinf(bb);
        s_g[tid][0] =  ca * c;  s_g[tid][1] = -sa * c;
        s_g[tid][2] = -cb * sn; s_g[tid][3] = -sb * sn;
        s_g[tid][4] =  cb * sn; s_g[tid][5] = -sb * sn;
        s_g[tid][6] =  ca * c;  s_g[tid][7] =  sa * c;
    }
#pragma unroll
    for (int k = 0; k < 4; ++k) {
        const int i = tid + 256 * k;
        s_re[i] = x[b * NSTATE + i];
        s_im[i] = 0.0f;
    }
    __syncthreads();
    for (int l = 0; l < QDEPTH; ++l) {
        for (int q = 0; q < WIRES; ++q) {
            const int gi = l * WIRES + q;
            const float u00r = s_g[gi][0], u00i = s_g[gi][1];
            const float u01r = s_g[gi][2], u01i = s_g[gi][3];
            const float u10r = s_g[gi][4], u10i = s_g[gi][5];
            const float u11r = s_g[gi][6], u11i = s_g[gi][7];
            const int sh = 9 - q;
            const int m  = 1 << sh;
#pragma unroll
            for (int k = 0; k < 2; ++k) {
                const int p  = tid + 256 * k;
                const int i0 = ((p >> sh) << (sh + 1)) | (p & (m - 1));
                const int i1 = i0 | m;
                const float a0r = s_re[i0], a0i = s_im[i0];
                const float a1r = s_re[i1], a1i = s_im[i1];
                s_re[i0] = u00r*a0r - u00i*a0i + u01r*a1r - u01i*a1i;
                s_im[i0] = u00r*a0i + u00i*a0r + u01r*a1i + u01i*a1r;
                s_re[i1] = u10r*a0r - u10i*a0i + u11r*a1r - u11i*a1i;
                s_im[i1] = u10r*a0i + u10i*a0r + u11r*a1i + u11i*a1r;
            }
            __syncthreads();
        }
        const int r = (l % (WIRES - 1)) + 1;
        float vr[4], vi[4];
#pragma unroll
        for (int k = 0; k < 4; ++k) {
            const int i = tid + 256 * k;
            const int j = perm_g(i, r);
            vr[k] = s_re[j]; vi[k] = s_im[j];
        }
        __syncthreads();
#pragma unroll
        for (int k = 0; k < 4; ++k) {
            const int i = tid + 256 * k;
            s_re[i] = vr[k]; s_im[i] = vi[k];
        }
        __syncthreads();
    }
    if (interleaved) {
#pragma unroll
        for (int k = 0; k < 4; ++k) {
            const int i  = tid + 256 * k;
            const int fi = 2 * (b * NSTATE + i);
            out[fi + 0] = s_re[i];
            out[fi + 1] = s_im[i];
        }
    } else {
#pragma unroll
        for (int k = 0; k < 4; ++k) {
            const int i = tid + 256 * k;
            out[b * NSTATE + i] = s_re[i];
        }
    }
}

extern "C" void kernel_launch(void* const* d_in, const int* in_sizes, int n_in,
                              void* d_out, int out_size, void* d_ws, size_t ws_size,
                              hipStream_t stream) {
    const float* x       = (const float*)d_in[0];   // (2048,1,32,32) f32
    const float* weights = (const float*)d_in[1];   // (8,10,3) f32
    float* out = (float*)d_out;
    const int interleaved = (out_size >= 2 * NBATCH * NSTATE) ? 1 : 0;

    if (ws_size >= WS_WORDS * sizeof(float)) {
        float* ws = (float*)d_ws;
        qprep<<<1, 1024, 0, stream>>>(weights, ws);
        qsim_wave<<<NBATCH, 64, 0, stream>>>(x, ws, out, interleaved);
    } else {
        qcircuit_kernel<<<NBATCH, 256, 0, stream>>>(x, weights, out, interleaved);
    }
}